// Round 1
// baseline (515.044 us; speedup 1.0000x reference)
//
#include <hip/hip_runtime.h>
#include <hip/hip_bf16.h>

typedef __bf16 bf16;
typedef __bf16 bf16x4 __attribute__((ext_vector_type(4)));
typedef __bf16 bf16x8 __attribute__((ext_vector_type(8)));
typedef float f32x4 __attribute__((ext_vector_type(4)));

#define NB 4
#define SEQ 2048
#define DM 1024
#define NH 16
#define HDIM 64
#define MTOT (NB*SEQ)   // 8192

// async global -> LDS, 16 bytes per lane
#define ASYNC16(ldsp, gp) __builtin_amdgcn_global_load_lds( \
    (const __attribute__((address_space(1))) void*)(gp),    \
    (__attribute__((address_space(3))) void*)(ldsp), 16, 0, 0)

// ---------------- conversion kernels ----------------
__global__ void cvt_x_kernel(const float* __restrict__ x, bf16* __restrict__ xb, int n4) {
  int i = blockIdx.x * blockDim.x + threadIdx.x;
  int stride = gridDim.x * blockDim.x;
  for (; i < n4; i += stride) {
    float4 v = ((const float4*)x)[i];
    bf16x4 o = {(bf16)v.x, (bf16)v.y, (bf16)v.z, (bf16)v.w};
    ((bf16x4*)xb)[i] = o;
  }
}

// transpose + convert: wt[z][n][k] = w_z[k][n], bf16
__global__ void cvt_w_kernel(const float* __restrict__ w0, const float* __restrict__ w1,
                             const float* __restrict__ w2, const float* __restrict__ w3,
                             bf16* __restrict__ wt) {
  __shared__ float t[32][33];
  const float* w = blockIdx.z == 0 ? w0 : blockIdx.z == 1 ? w1 : blockIdx.z == 2 ? w2 : w3;
  bf16* o = wt + (size_t)blockIdx.z * DM * DM;
  int n0 = blockIdx.x * 32, k0 = blockIdx.y * 32;
  int tx = threadIdx.x, ty = threadIdx.y;   // 32 x 8
  #pragma unroll
  for (int i = 0; i < 4; i++) t[ty + 8*i][tx] = w[(size_t)(k0 + ty + 8*i) * DM + n0 + tx];
  __syncthreads();
  #pragma unroll
  for (int i = 0; i < 4; i++) o[(size_t)(n0 + ty + 8*i) * DM + k0 + tx] = (bf16)t[tx][ty + 8*i];
}

// ---------------- 128x128 bf16 GEMM, A[M][K] * Bt[N][K]^T ----------------
// EPI 0: QKV projection epilogue (scatter to per-head q/k and transposed v)
// EPI 1: output projection epilogue (fp32 write + bias)
template<int EPI>
__global__ __launch_bounds__(256) void gemm128(
    const bf16* __restrict__ A, const bf16* __restrict__ Bt,
    const float* __restrict__ bq, const float* __restrict__ bk, const float* __restrict__ bv,
    bf16* __restrict__ oq, bf16* __restrict__ ok, bf16* __restrict__ ovt,
    float* __restrict__ of) {
  const int tid = threadIdx.x;
  const int lane = tid & 63;
  const int wid = tid >> 6;
  const int wr = wid >> 1, wc = wid & 1;     // 2x2 waves, each 64x64
  const int bm = blockIdx.y * 128;
  const int bn = blockIdx.x * 128;

  __shared__ __align__(16) bf16 As[2][128 * 32];
  __shared__ __align__(16) bf16 Bs[2][128 * 32];

  f32x4 acc[4][4] = {};

  const bf16* ga = A  + (size_t)(bm + (tid >> 2)) * DM + (tid & 3) * 8;
  const bf16* gb = Bt + (size_t)(bn + (tid >> 2)) * DM + (tid & 3) * 8;

  // stage K-tile 0 into buffer 0
  ASYNC16(&As[0][tid * 8], ga);
  ASYNC16(&As[0][2048 + tid * 8], ga + 64 * DM);
  ASYNC16(&Bs[0][tid * 8], gb);
  ASYNC16(&Bs[0][2048 + tid * 8], gb + 64 * DM);

  const int r0 = lane & 15;
  const int kc = (lane >> 4) * 8;

  for (int kt = 0; kt < DM / 32; ++kt) {
    const int cur = kt & 1;
    __syncthreads();                        // drains vmcnt: buffer `cur` staged, prev compute done
    if (kt + 1 < DM / 32) {
      const int nk = (kt + 1) * 32;
      ASYNC16(&As[cur ^ 1][tid * 8], ga + nk);
      ASYNC16(&As[cur ^ 1][2048 + tid * 8], ga + 64 * DM + nk);
      ASYNC16(&Bs[cur ^ 1][tid * 8], gb + nk);
      ASYNC16(&Bs[cur ^ 1][2048 + tid * 8], gb + 64 * DM + nk);
    }
    bf16x8 af[4], bfr[4];
    #pragma unroll
    for (int i = 0; i < 4; i++) {
      af[i]  = *(const bf16x8*)&As[cur][(wr * 64 + i * 16 + r0) * 32 + kc];
      bfr[i] = *(const bf16x8*)&Bs[cur][(wc * 64 + i * 16 + r0) * 32 + kc];
    }
    #pragma unroll
    for (int i = 0; i < 4; i++)
      #pragma unroll
      for (int j = 0; j < 4; j++)
        acc[i][j] = __builtin_amdgcn_mfma_f32_16x16x32_bf16(af[i], bfr[j], acc[i][j], 0, 0, 0);
  }

  if (EPI == 0) {
    const int which = bn >> 10;                       // block-uniform (128 | 1024)
    const float* bp = which == 0 ? bq : which == 1 ? bk : bv;
    #pragma unroll
    for (int j = 0; j < 4; j++) {
      const int n = bn + wc * 64 + j * 16 + r0;
      const int dcol = n & 1023;
      const int h = dcol >> 6, hd = dcol & 63;
      const float bias = bp[dcol];
      #pragma unroll
      for (int i = 0; i < 4; i++)
        #pragma unroll
        for (int r = 0; r < 4; r++) {
          const int m = bm + wr * 64 + i * 16 + (lane >> 4) * 4 + r;
          const int b_ = m >> 11, s_ = m & 2047;
          const float v = acc[i][j][r] + bias;
          if (which == 0)
            oq[(((size_t)b_ * NH + h) * SEQ + s_) * HDIM + hd] = (bf16)v;
          else if (which == 1)
            ok[(((size_t)b_ * NH + h) * SEQ + s_) * HDIM + hd] = (bf16)v;
          else
            ovt[(((size_t)b_ * NH + h) * HDIM + hd) * SEQ + s_] = (bf16)v;
        }
    }
  } else {
    #pragma unroll
    for (int j = 0; j < 4; j++) {
      const int n = bn + wc * 64 + j * 16 + r0;
      const float bias = bq[n];                        // o_b
      #pragma unroll
      for (int i = 0; i < 4; i++)
        #pragma unroll
        for (int r = 0; r < 4; r++) {
          const int m = bm + wr * 64 + i * 16 + (lane >> 4) * 4 + r;
          of[(size_t)m * DM + n] = acc[i][j][r] + bias;
        }
    }
  }
}

// ---------------- flash attention ----------------
// grid (S/64, H, B), 256 threads = 4 waves, each wave owns 16 q-rows
__global__ __launch_bounds__(256) void attn_kernel(
    const bf16* __restrict__ Q, const bf16* __restrict__ Kmat, const bf16* __restrict__ Vt,
    bf16* __restrict__ O) {
  const int tid = threadIdx.x;
  const int lane = tid & 63;
  const int wid = tid >> 6;
  const int qt = blockIdx.x;
  const int h = blockIdx.y;
  const int b = blockIdx.z;

  const bf16* q  = Q    + (((size_t)b * NH + h) * SEQ + qt * 64) * HDIM;
  const bf16* kp = Kmat + ((size_t)b * NH + h) * SEQ * HDIM;
  const bf16* vp = Vt   + ((size_t)b * NH + h) * HDIM * SEQ;

  __shared__ __align__(16) bf16 Qs[64 * 64];
  __shared__ __align__(16) bf16 Ks[2][64 * 64];
  __shared__ __align__(16) bf16 Vs[2][64 * 64];     // Vs[d][kv] (v transposed)
  __shared__ __align__(16) bf16 Ps[4][16 * 64];     // per-wave P tile

  {
    const bf16* gq = q + (tid >> 3) * HDIM + (tid & 7) * 8;
    ASYNC16(&Qs[tid * 8], gq);
    ASYNC16(&Qs[2048 + tid * 8], gq + 32 * HDIM);
    const bf16* gk = kp + (tid >> 3) * HDIM + (tid & 7) * 8;
    ASYNC16(&Ks[0][tid * 8], gk);
    ASYNC16(&Ks[0][2048 + tid * 8], gk + 32 * HDIM);
    const bf16* gv = vp + (size_t)(tid >> 3) * SEQ + (tid & 7) * 8;
    ASYNC16(&Vs[0][tid * 8], gv);
    ASYNC16(&Vs[0][2048 + tid * 8], gv + (size_t)32 * SEQ);
  }

  f32x4 m_run, l_run;
  f32x4 oacc[4] = {};
  #pragma unroll
  for (int r = 0; r < 4; r++) { m_run[r] = -1e30f; l_run[r] = 0.f; }

  const int r0 = lane & 15;
  const int kc8 = (lane >> 4) * 8;

  for (int kt = 0; kt < SEQ / 64; ++kt) {
    const int cur = kt & 1;
    __syncthreads();
    if (kt + 1 < SEQ / 64) {
      const bf16* gk = kp + (size_t)(kt + 1) * 64 * HDIM + (tid >> 3) * HDIM + (tid & 7) * 8;
      ASYNC16(&Ks[cur ^ 1][tid * 8], gk);
      ASYNC16(&Ks[cur ^ 1][2048 + tid * 8], gk + 32 * HDIM);
      const bf16* gv = vp + (size_t)(tid >> 3) * SEQ + (kt + 1) * 64 + (tid & 7) * 8;
      ASYNC16(&Vs[cur ^ 1][tid * 8], gv);
      ASYNC16(&Vs[cur ^ 1][2048 + tid * 8], gv + (size_t)32 * SEQ);
    }

    // ---- QK^T : 16 q-rows x 64 k-cols ----
    f32x4 sc[4] = {};
    #pragma unroll
    for (int c = 0; c < 2; c++) {
      const bf16x8 aq = *(const bf16x8*)&Qs[(wid * 16 + r0) * 64 + c * 32 + kc8];
      #pragma unroll
      for (int nf = 0; nf < 4; nf++) {
        const bf16x8 bk = *(const bf16x8*)&Ks[cur][(nf * 16 + r0) * 64 + c * 32 + kc8];
        sc[nf] = __builtin_amdgcn_mfma_f32_16x16x32_bf16(aq, bk, sc[nf], 0, 0, 0);
      }
    }

    // ---- online softmax ----
    f32x4 tmax;
    #pragma unroll
    for (int r = 0; r < 4; r++) {
      sc[0][r] *= 0.125f; sc[1][r] *= 0.125f; sc[2][r] *= 0.125f; sc[3][r] *= 0.125f;
      tmax[r] = fmaxf(fmaxf(sc[0][r], sc[1][r]), fmaxf(sc[2][r], sc[3][r]));
    }
    #pragma unroll
    for (int d = 1; d < 16; d <<= 1)
      #pragma unroll
      for (int r = 0; r < 4; r++)
        tmax[r] = fmaxf(tmax[r], __shfl_xor(tmax[r], d));

    f32x4 mnew, fac, psum;
    #pragma unroll
    for (int r = 0; r < 4; r++) {
      mnew[r] = fmaxf(m_run[r], tmax[r]);
      fac[r]  = __expf(m_run[r] - mnew[r]);
      psum[r] = 0.f;
    }
    #pragma unroll
    for (int nf = 0; nf < 4; nf++)
      #pragma unroll
      for (int r = 0; r < 4; r++) {
        const float pv = __expf(sc[nf][r] - mnew[r]);
        psum[r] += pv;
        Ps[wid][((lane >> 4) * 4 + r) * 64 + nf * 16 + r0] = (bf16)pv;
      }
    #pragma unroll
    for (int d = 1; d < 16; d <<= 1)
      #pragma unroll
      for (int r = 0; r < 4; r++)
        psum[r] += __shfl_xor(psum[r], d);
    #pragma unroll
    for (int r = 0; r < 4; r++) {
      l_run[r] = l_run[r] * fac[r] + psum[r];
      m_run[r] = mnew[r];
    }
    #pragma unroll
    for (int df = 0; df < 4; df++)
      #pragma unroll
      for (int r = 0; r < 4; r++)
        oacc[df][r] *= fac[r];

    // ---- PV ----
    #pragma unroll
    for (int c = 0; c < 2; c++) {
      const bf16x8 ap = *(const bf16x8*)&Ps[wid][r0 * 64 + c * 32 + kc8];
      #pragma unroll
      for (int df = 0; df < 4; df++) {
        const bf16x8 bv = *(const bf16x8*)&Vs[cur][(df * 16 + r0) * 64 + c * 32 + kc8];
        oacc[df] = __builtin_amdgcn_mfma_f32_16x16x32_bf16(ap, bv, oacc[df], 0, 0, 0);
      }
    }
  }

  // ---- epilogue: normalize, write attn output [B][S][D] (bf16) ----
  #pragma unroll
  for (int r = 0; r < 4; r++) l_run[r] = 1.0f / l_run[r];
  #pragma unroll
  for (int df = 0; df < 4; df++)
    #pragma unroll
    for (int r = 0; r < 4; r++) {
      const int qrow = qt * 64 + wid * 16 + (lane >> 4) * 4 + r;
      O[((size_t)b * SEQ + qrow) * DM + h * HDIM + df * 16 + r0] = (bf16)(oacc[df][r] * l_run[r]);
    }
}

// ---------------- launcher ----------------
extern "C" void kernel_launch(void* const* d_in, const int* in_sizes, int n_in,
                              void* d_out, int out_size, void* d_ws, size_t ws_size,
                              hipStream_t stream) {
  (void)in_sizes; (void)n_in; (void)out_size; (void)ws_size;
  const float* x   = (const float*)d_in[0];
  const float* q_w = (const float*)d_in[1];
  const float* q_b = (const float*)d_in[2];
  const float* k_w = (const float*)d_in[3];
  const float* k_b = (const float*)d_in[4];
  const float* v_w = (const float*)d_in[5];
  const float* v_b = (const float*)d_in[6];
  const float* o_w = (const float*)d_in[7];
  const float* o_b = (const float*)d_in[8];
  float* out = (float*)d_out;

  char* p = (char*)d_ws;
  bf16* xb = (bf16*)p;  p += (size_t)MTOT * DM * 2;   // x bf16; reused later as attn output
  bf16* wt = (bf16*)p;  p += (size_t)4 * DM * DM * 2; // transposed bf16 weights [4][N][K]
  bf16* qq = (bf16*)p;  p += (size_t)MTOT * DM * 2;   // Q [B][H][S][HD]
  bf16* kk = (bf16*)p;  p += (size_t)MTOT * DM * 2;   // K [B][H][S][HD]
  bf16* vt = (bf16*)p;  p += (size_t)MTOT * DM * 2;   // V^T [B][H][HD][S]

  cvt_x_kernel<<<1024, 256, 0, stream>>>(x, xb, MTOT * DM / 4);
  cvt_w_kernel<<<dim3(32, 32, 4), dim3(32, 8), 0, stream>>>(q_w, k_w, v_w, o_w, wt);

  // QKV projection: M=8192, N=3072 (q|k|v), K=1024
  gemm128<0><<<dim3(24, 64), 256, 0, stream>>>(xb, wt, q_b, k_b, v_b, qq, kk, vt, nullptr);

  // flash attention, writes [B][S][D] bf16 into xb (x no longer needed)
  attn_kernel<<<dim3(SEQ / 64, NH, NB), 256, 0, stream>>>(qq, kk, vt, xb);

  // output projection: M=8192, N=1024, K=1024, fp32 out + bias
  gemm128<1><<<dim3(8, 64), 256, 0, stream>>>(xb, wt + (size_t)3 * DM * DM, o_b, nullptr, nullptr,
                                              nullptr, nullptr, nullptr, out);
}

// Round 4
// 430.126 us; speedup vs baseline: 1.1974x; 1.1974x over previous
//
#include <hip/hip_runtime.h>
#include <hip/hip_bf16.h>

typedef __bf16 bf16;
typedef __bf16 bf16x4 __attribute__((ext_vector_type(4)));
typedef __bf16 bf16x8 __attribute__((ext_vector_type(8)));
typedef float f32x4 __attribute__((ext_vector_type(4)));

#define NB 4
#define SEQ 2048
#define DM 1024
#define NH 16
#define HDIM 64
#define MTOT (NB*SEQ)   // 8192

// 0.125 * log2(e): folded into Q at the QKV epilogue so softmax uses exp2
#define QSCALE 0.18033688011112042f

// async global -> LDS, 16 bytes per lane
#define ASYNC16(ldsp, gp) __builtin_amdgcn_global_load_lds( \
    (const __attribute__((address_space(1))) void*)(gp),    \
    (__attribute__((address_space(3))) void*)(ldsp), 16, 0, 0)

// ---------------- conversion kernels ----------------
__global__ void cvt_x_kernel(const float* __restrict__ x, bf16* __restrict__ xb, int n4) {
  int i = blockIdx.x * blockDim.x + threadIdx.x;
  int stride = gridDim.x * blockDim.x;
  for (; i < n4; i += stride) {
    float4 v = ((const float4*)x)[i];
    bf16x4 o = {(bf16)v.x, (bf16)v.y, (bf16)v.z, (bf16)v.w};
    ((bf16x4*)xb)[i] = o;
  }
}

// transpose + convert: wt[z][n][k] = w_z[k][n], bf16
__global__ void cvt_w_kernel(const float* __restrict__ w0, const float* __restrict__ w1,
                             const float* __restrict__ w2, const float* __restrict__ w3,
                             bf16* __restrict__ wt) {
  __shared__ float t[32][33];
  const float* w = blockIdx.z == 0 ? w0 : blockIdx.z == 1 ? w1 : blockIdx.z == 2 ? w2 : w3;
  bf16* o = wt + (size_t)blockIdx.z * DM * DM;
  int n0 = blockIdx.x * 32, k0 = blockIdx.y * 32;
  int tx = threadIdx.x, ty = threadIdx.y;   // 32 x 8
  #pragma unroll
  for (int i = 0; i < 4; i++) t[ty + 8*i][tx] = w[(size_t)(k0 + ty + 8*i) * DM + n0 + tx];
  __syncthreads();
  #pragma unroll
  for (int i = 0; i < 4; i++) o[(size_t)(n0 + ty + 8*i) * DM + k0 + tx] = (bf16)t[tx][ty + 8*i];
}

// ---------------- 128x128 bf16 GEMM, A[M][K] * Bt[N][K]^T ----------------
// EPI 0: QKV projection epilogue -> fragment-ordered Q/K/V layouts
//   Q/K per (b,h), per 16-row block (1024 elems): off = c*512 + g*128 + r*8 + j
//       c=hd>>5, g=(hd>>3)&3, r=s&15, j=hd&7
//   V   per (b,h), per 64-kv tile (4096 elems): off = df*1024 + c*512 + g*128 + r*8 + j
//       df=hd>>4, c=(s>>5)&1, g=(s>>3)&3, r=hd&15, j=s&7
// EPI 1: output projection epilogue (fp32 write + bias)
template<int EPI>
__global__ __launch_bounds__(256) void gemm128(
    const bf16* __restrict__ A, const bf16* __restrict__ Bt,
    const float* __restrict__ bq, const float* __restrict__ bk, const float* __restrict__ bv,
    bf16* __restrict__ oq, bf16* __restrict__ ok, bf16* __restrict__ ovt,
    float* __restrict__ of) {
  const int tid = threadIdx.x;
  const int lane = tid & 63;
  const int wid = tid >> 6;
  const int wr = wid >> 1, wc = wid & 1;     // 2x2 waves, each 64x64
  const int bm = blockIdx.y * 128;
  const int bn = blockIdx.x * 128;

  __shared__ __align__(16) bf16 As[2][128 * 32];
  __shared__ __align__(16) bf16 Bs[2][128 * 32];

  f32x4 acc[4][4] = {};

  const bf16* ga = A  + (size_t)(bm + (tid >> 2)) * DM + (tid & 3) * 8;
  const bf16* gb = Bt + (size_t)(bn + (tid >> 2)) * DM + (tid & 3) * 8;

  // stage K-tile 0 into buffer 0
  ASYNC16(&As[0][tid * 8], ga);
  ASYNC16(&As[0][2048 + tid * 8], ga + 64 * DM);
  ASYNC16(&Bs[0][tid * 8], gb);
  ASYNC16(&Bs[0][2048 + tid * 8], gb + 64 * DM);

  const int r0 = lane & 15;
  const int kc = (lane >> 4) * 8;

  for (int kt = 0; kt < DM / 32; ++kt) {
    const int cur = kt & 1;
    __syncthreads();
    if (kt + 1 < DM / 32) {
      const int nk = (kt + 1) * 32;
      ASYNC16(&As[cur ^ 1][tid * 8], ga + nk);
      ASYNC16(&As[cur ^ 1][2048 + tid * 8], ga + 64 * DM + nk);
      ASYNC16(&Bs[cur ^ 1][tid * 8], gb + nk);
      ASYNC16(&Bs[cur ^ 1][2048 + tid * 8], gb + 64 * DM + nk);
    }
    bf16x8 af[4], bfr[4];
    #pragma unroll
    for (int i = 0; i < 4; i++) {
      af[i]  = *(const bf16x8*)&As[cur][(wr * 64 + i * 16 + r0) * 32 + kc];
      bfr[i] = *(const bf16x8*)&Bs[cur][(wc * 64 + i * 16 + r0) * 32 + kc];
    }
    #pragma unroll
    for (int i = 0; i < 4; i++)
      #pragma unroll
      for (int j = 0; j < 4; j++)
        acc[i][j] = __builtin_amdgcn_mfma_f32_16x16x32_bf16(af[i], bfr[j], acc[i][j], 0, 0, 0);
  }

  if (EPI == 0) {
    const int which = bn >> 10;                       // block-uniform (0:q 1:k 2:v)
    const float* bp = which == 0 ? bq : which == 1 ? bk : bv;
    const float scale = (which == 0) ? QSCALE : 1.0f;
    #pragma unroll
    for (int j = 0; j < 4; j++) {
      const int n = bn + wc * 64 + j * 16 + r0;
      const int dcol = n & 1023;
      const int h = dcol >> 6, hd = dcol & 63;
      const float bias = bp[dcol];
      // hd-dependent offsets, hoisted
      const int qk_d = ((hd >> 5) * 4 + ((hd >> 3) & 3)) * 128 + (hd & 7);
      const int v_d  = (hd >> 4) * 1024 + (hd & 15) * 8;
      #pragma unroll
      for (int i = 0; i < 4; i++)
        #pragma unroll
        for (int r = 0; r < 4; r++) {
          const int m = bm + wr * 64 + i * 16 + (lane >> 4) * 4 + r;
          const int b_ = m >> 11, s_ = m & 2047;
          const float v = (acc[i][j][r] + bias) * scale;
          if (which <= 1) {
            const size_t off = ((size_t)(b_ * NH + h) * (SEQ / 16) + (s_ >> 4)) * 1024
                             + qk_d + (s_ & 15) * 8;
            (which == 0 ? oq : ok)[off] = (bf16)v;
          } else {
            const size_t off = ((size_t)(b_ * NH + h) * (SEQ / 64) + (s_ >> 6)) * 4096
                             + v_d + ((s_ >> 5) & 1) * 512 + ((s_ >> 3) & 3) * 128 + (s_ & 7);
            ovt[off] = (bf16)v;
          }
        }
    }
  } else {
    #pragma unroll
    for (int j = 0; j < 4; j++) {
      const int n = bn + wc * 64 + j * 16 + r0;
      const float bias = bq[n];                        // o_b
      #pragma unroll
      for (int i = 0; i < 4; i++)
        #pragma unroll
        for (int r = 0; r < 4; r++) {
          const int m = bm + wr * 64 + i * 16 + (lane >> 4) * 4 + r;
          of[(size_t)m * DM + n] = acc[i][j][r] + bias;
        }
    }
  }
}

// ---------------- flash attention (fragment-ordered Q/K/V) ----------------
// grid (S/64, H, B), 256 threads = 4 waves, each wave owns 16 q-rows
__global__ __launch_bounds__(256) void attn_kernel(
    const bf16* __restrict__ Q, const bf16* __restrict__ Kf, const bf16* __restrict__ Vf,
    bf16* __restrict__ O) {
  const int tid = threadIdx.x;
  const int lane = tid & 63;
  const int wid = tid >> 6;
  const int gq = lane >> 4;
  const int r0 = lane & 15;
  const int qt = blockIdx.x;
  const int h = blockIdx.y;
  const int b = blockIdx.z;

  const bf16* qp = Q  + ((size_t)(b * NH + h) * (SEQ / 16) + qt * 4) * 1024;
  const bf16* kp = Kf + (size_t)(b * NH + h) * (SEQ / 16) * 1024;
  const bf16* vp = Vf + (size_t)(b * NH + h) * (SEQ / 64) * 4096;

  __shared__ __align__(16) bf16 Ks[2][4096];
  __shared__ __align__(16) bf16 Vs[2][4096];   // fragment-ordered V tile
  __shared__ __align__(16) bf16 Ps[4][1024];   // per-wave P tile, fragment-ordered

  // stage Q (into Ks[1], read-once), K0, V0
  ASYNC16(&Ks[1][tid * 8], qp + tid * 8);
  ASYNC16(&Ks[1][2048 + tid * 8], qp + 2048 + tid * 8);
  ASYNC16(&Ks[0][tid * 8], kp + tid * 8);
  ASYNC16(&Ks[0][2048 + tid * 8], kp + 2048 + tid * 8);
  ASYNC16(&Vs[0][tid * 8], vp + tid * 8);
  ASYNC16(&Vs[0][2048 + tid * 8], vp + 2048 + tid * 8);
  __syncthreads();

  // Q fragments are loop-invariant: keep in registers
  const bf16x8 aq0 = *(const bf16x8*)&Ks[1][((wid * 2 + 0) * 4 + gq) * 128 + r0 * 8];
  const bf16x8 aq1 = *(const bf16x8*)&Ks[1][((wid * 2 + 1) * 4 + gq) * 128 + r0 * 8];
  __syncthreads();   // all waves done reading Q before Ks[1] is overwritten

  f32x4 m_run, l_run;
  f32x4 oacc[4] = {};
  #pragma unroll
  for (int r = 0; r < 4; r++) { m_run[r] = -1e30f; l_run[r] = 0.f; }

  for (int kt = 0; kt < SEQ / 64; ++kt) {
    const int cur = kt & 1;
    if (kt + 1 < SEQ / 64) {
      const bf16* gk = kp + (size_t)(kt + 1) * 4096;
      ASYNC16(&Ks[cur ^ 1][tid * 8], gk + tid * 8);
      ASYNC16(&Ks[cur ^ 1][2048 + tid * 8], gk + 2048 + tid * 8);
      const bf16* gv = vp + (size_t)(kt + 1) * 4096;
      ASYNC16(&Vs[cur ^ 1][tid * 8], gv + tid * 8);
      ASYNC16(&Vs[cur ^ 1][2048 + tid * 8], gv + 2048 + tid * 8);
    }

    // ---- QK^T : 16 q-rows x 64 k-cols (Q pre-scaled by 0.125*log2e) ----
    f32x4 sc[4] = {};
    __builtin_amdgcn_s_setprio(1);
    #pragma unroll
    for (int nf = 0; nf < 4; nf++) {
      const bf16x8 bk0 = *(const bf16x8*)&Ks[cur][((nf * 2 + 0) * 4 + gq) * 128 + r0 * 8];
      sc[nf] = __builtin_amdgcn_mfma_f32_16x16x32_bf16(aq0, bk0, sc[nf], 0, 0, 0);
      const bf16x8 bk1 = *(const bf16x8*)&Ks[cur][((nf * 2 + 1) * 4 + gq) * 128 + r0 * 8];
      sc[nf] = __builtin_amdgcn_mfma_f32_16x16x32_bf16(aq1, bk1, sc[nf], 0, 0, 0);
    }
    __builtin_amdgcn_s_setprio(0);

    // ---- online softmax (log2 domain) ----
    f32x4 tmax;
    #pragma unroll
    for (int r = 0; r < 4; r++)
      tmax[r] = fmaxf(fmaxf(sc[0][r], sc[1][r]), fmaxf(sc[2][r], sc[3][r]));
    #pragma unroll
    for (int d = 1; d < 16; d <<= 1)
      #pragma unroll
      for (int r = 0; r < 4; r++)
        tmax[r] = fmaxf(tmax[r], __shfl_xor(tmax[r], d));

    f32x4 mnew, fac, psum;
    #pragma unroll
    for (int r = 0; r < 4; r++) {
      mnew[r] = fmaxf(m_run[r], tmax[r]);
      fac[r]  = exp2f(m_run[r] - mnew[r]);
      psum[r] = 0.f;
    }
    #pragma unroll
    for (int nf = 0; nf < 4; nf++) {
      const int pblk = ((nf >> 1) * 4 + ((nf * 2 + (r0 >> 3)) & 3)) * 128 + (r0 & 7);
      #pragma unroll
      for (int r = 0; r < 4; r++) {
        const float pv = exp2f(sc[nf][r] - mnew[r]);
        psum[r] += pv;
        Ps[wid][pblk + (gq * 4 + r) * 8] = (bf16)pv;
      }
    }
    #pragma unroll
    for (int d = 1; d < 16; d <<= 1)
      #pragma unroll
      for (int r = 0; r < 4; r++)
        psum[r] += __shfl_xor(psum[r], d);
    #pragma unroll
    for (int r = 0; r < 4; r++) {
      l_run[r] = l_run[r] * fac[r] + psum[r];
      m_run[r] = mnew[r];
    }
    #pragma unroll
    for (int df = 0; df < 4; df++)
      #pragma unroll
      for (int r = 0; r < 4; r++)
        oacc[df][r] *= fac[r];

    // ---- PV (fragment-ordered Ps and Vs: conflict-free b128 reads) ----
    __builtin_amdgcn_s_setprio(1);
    #pragma unroll
    for (int c = 0; c < 2; c++) {
      const bf16x8 ap = *(const bf16x8*)&Ps[wid][(c * 4 + gq) * 128 + r0 * 8];
      #pragma unroll
      for (int df = 0; df < 4; df++) {
        const bf16x8 bv = *(const bf16x8*)&Vs[cur][((df * 2 + c) * 4 + gq) * 128 + r0 * 8];
        oacc[df] = __builtin_amdgcn_mfma_f32_16x16x32_bf16(ap, bv, oacc[df], 0, 0, 0);
      }
    }
    __builtin_amdgcn_s_setprio(0);
    __syncthreads();   // compute done + this iter's staging landed
  }

  // ---- epilogue: normalize, write attn output [B][S][D] (bf16) ----
  #pragma unroll
  for (int r = 0; r < 4; r++) l_run[r] = 1.0f / l_run[r];
  #pragma unroll
  for (int df = 0; df < 4; df++)
    #pragma unroll
    for (int r = 0; r < 4; r++) {
      const int qrow = qt * 64 + wid * 16 + gq * 4 + r;
      O[((size_t)b * SEQ + qrow) * DM + h * HDIM + df * 16 + r0] = (bf16)(oacc[df][r] * l_run[r]);
    }
}

// ---------------- launcher ----------------
extern "C" void kernel_launch(void* const* d_in, const int* in_sizes, int n_in,
                              void* d_out, int out_size, void* d_ws, size_t ws_size,
                              hipStream_t stream) {
  (void)in_sizes; (void)n_in; (void)out_size; (void)ws_size;
  const float* x   = (const float*)d_in[0];
  const float* q_w = (const float*)d_in[1];
  const float* q_b = (const float*)d_in[2];
  const float* k_w = (const float*)d_in[3];
  const float* k_b = (const float*)d_in[4];
  const float* v_w = (const float*)d_in[5];
  const float* v_b = (const float*)d_in[6];
  const float* o_w = (const float*)d_in[7];
  const float* o_b = (const float*)d_in[8];
  float* out = (float*)d_out;

  char* p = (char*)d_ws;
  bf16* xb = (bf16*)p;  p += (size_t)MTOT * DM * 2;   // x bf16; reused later as attn output
  bf16* wt = (bf16*)p;  p += (size_t)4 * DM * DM * 2; // transposed bf16 weights [4][N][K]
  bf16* qq = (bf16*)p;  p += (size_t)MTOT * DM * 2;   // Q fragment-ordered (pre-scaled)
  bf16* kk = (bf16*)p;  p += (size_t)MTOT * DM * 2;   // K fragment-ordered
  bf16* vt = (bf16*)p;  p += (size_t)MTOT * DM * 2;   // V fragment-ordered

  cvt_x_kernel<<<1024, 256, 0, stream>>>(x, xb, MTOT * DM / 4);
  cvt_w_kernel<<<dim3(32, 32, 4), dim3(32, 8), 0, stream>>>(q_w, k_w, v_w, o_w, wt);

  // QKV projection: M=8192, N=3072 (q|k|v), K=1024
  gemm128<0><<<dim3(24, 64), 256, 0, stream>>>(xb, wt, q_b, k_b, v_b, qq, kk, vt, nullptr);

  // flash attention, writes [B][S][D] bf16 into xb (x no longer needed)
  attn_kernel<<<dim3(SEQ / 64, NH, NB), 256, 0, stream>>>(qq, kk, vt, xb);

  // output projection: M=8192, N=1024, K=1024, fp32 out + bias
  gemm128<1><<<dim3(8, 64), 256, 0, stream>>>(xb, wt + (size_t)3 * DM * DM, o_b, nullptr, nullptr,
                                              nullptr, nullptr, nullptr, out);
}

// Round 6
// 372.775 us; speedup vs baseline: 1.3816x; 1.1538x over previous
//
#include <hip/hip_runtime.h>
#include <hip/hip_bf16.h>

typedef __bf16 bf16;
typedef __bf16 bf16x4 __attribute__((ext_vector_type(4)));
typedef __bf16 bf16x8 __attribute__((ext_vector_type(8)));
typedef float f32x4 __attribute__((ext_vector_type(4)));

#define NB 4
#define SEQ 2048
#define DM 1024
#define NH 16
#define HDIM 64
#define MTOT (NB*SEQ)   // 8192

// 0.125 * log2(e): folded into Q at the QKV epilogue so softmax uses exp2
#define QSCALE 0.18033688011112042f

// async global -> LDS, 16 bytes per lane
#define ASYNC16(ldsp, gp) __builtin_amdgcn_global_load_lds( \
    (const __attribute__((address_space(1))) void*)(gp),    \
    (__attribute__((address_space(3))) void*)(ldsp), 16, 0, 0)

// ---------------- conversion kernels ----------------
__global__ void cvt_x_kernel(const float* __restrict__ x, bf16* __restrict__ xb, int n4) {
  int i = blockIdx.x * blockDim.x + threadIdx.x;
  int stride = gridDim.x * blockDim.x;
  for (; i < n4; i += stride) {
    float4 v = ((const float4*)x)[i];
    bf16x4 o = {(bf16)v.x, (bf16)v.y, (bf16)v.z, (bf16)v.w};
    ((bf16x4*)xb)[i] = o;
  }
}

// transpose + convert: wt[z][n][k] = w_z[k][n], bf16
__global__ void cvt_w_kernel(const float* __restrict__ w0, const float* __restrict__ w1,
                             const float* __restrict__ w2, const float* __restrict__ w3,
                             bf16* __restrict__ wt) {
  __shared__ float t[32][33];
  const float* w = blockIdx.z == 0 ? w0 : blockIdx.z == 1 ? w1 : blockIdx.z == 2 ? w2 : w3;
  bf16* o = wt + (size_t)blockIdx.z * DM * DM;
  int n0 = blockIdx.x * 32, k0 = blockIdx.y * 32;
  int tx = threadIdx.x, ty = threadIdx.y;   // 32 x 8
  #pragma unroll
  for (int i = 0; i < 4; i++) t[ty + 8*i][tx] = w[(size_t)(k0 + ty + 8*i) * DM + n0 + tx];
  __syncthreads();
  #pragma unroll
  for (int i = 0; i < 4; i++) o[(size_t)(n0 + ty + 8*i) * DM + k0 + tx] = (bf16)t[tx][ty + 8*i];
}

// ---------------- 128x128 bf16 GEMM, A[M][K] * Bt[N][K]^T ----------------
// EPI 0: QKV projection epilogue -> fragment-ordered Q/K/V layouts
//   Q/K per (b,h), per 16-row block (1024 elems): off = c*512 + g*128 + r*8 + j
//       c=hd>>5, g=(hd>>3)&3, r=s&15, j=hd&7
//   V   per (b,h), per 64-kv tile (4096 elems): off = df*1024 + c*512 + g*128 + r*8 + j
//       df=hd>>4, c=(s>>5)&1, g=(s>>3)&3, r=hd&15, j=s&7
// EPI 1: output projection epilogue (fp32 write + bias)
template<int EPI>
__global__ __launch_bounds__(256) void gemm128(
    const bf16* __restrict__ A, const bf16* __restrict__ Bt,
    const float* __restrict__ bq, const float* __restrict__ bk, const float* __restrict__ bv,
    bf16* __restrict__ oq, bf16* __restrict__ ok, bf16* __restrict__ ovt,
    float* __restrict__ of) {
  const int tid = threadIdx.x;
  const int lane = tid & 63;
  const int wid = tid >> 6;
  const int wr = wid >> 1, wc = wid & 1;     // 2x2 waves, each 64x64
  const int bm = blockIdx.y * 128;
  const int bn = blockIdx.x * 128;

  __shared__ __align__(16) bf16 As[2][128 * 32];
  __shared__ __align__(16) bf16 Bs[2][128 * 32];

  f32x4 acc[4][4] = {};

  const bf16* ga = A  + (size_t)(bm + (tid >> 2)) * DM + (tid & 3) * 8;
  const bf16* gb = Bt + (size_t)(bn + (tid >> 2)) * DM + (tid & 3) * 8;

  // stage K-tile 0 into buffer 0
  ASYNC16(&As[0][tid * 8], ga);
  ASYNC16(&As[0][2048 + tid * 8], ga + 64 * DM);
  ASYNC16(&Bs[0][tid * 8], gb);
  ASYNC16(&Bs[0][2048 + tid * 8], gb + 64 * DM);

  const int r0 = lane & 15;
  const int kc = (lane >> 4) * 8;

  for (int kt = 0; kt < DM / 32; ++kt) {
    const int cur = kt & 1;
    __syncthreads();
    if (kt + 1 < DM / 32) {
      const int nk = (kt + 1) * 32;
      ASYNC16(&As[cur ^ 1][tid * 8], ga + nk);
      ASYNC16(&As[cur ^ 1][2048 + tid * 8], ga + 64 * DM + nk);
      ASYNC16(&Bs[cur ^ 1][tid * 8], gb + nk);
      ASYNC16(&Bs[cur ^ 1][2048 + tid * 8], gb + 64 * DM + nk);
    }
    bf16x8 af[4], bfr[4];
    #pragma unroll
    for (int i = 0; i < 4; i++) {
      af[i]  = *(const bf16x8*)&As[cur][(wr * 64 + i * 16 + r0) * 32 + kc];
      bfr[i] = *(const bf16x8*)&Bs[cur][(wc * 64 + i * 16 + r0) * 32 + kc];
    }
    #pragma unroll
    for (int i = 0; i < 4; i++)
      #pragma unroll
      for (int j = 0; j < 4; j++)
        acc[i][j] = __builtin_amdgcn_mfma_f32_16x16x32_bf16(af[i], bfr[j], acc[i][j], 0, 0, 0);
  }

  if (EPI == 0) {
    const int which = bn >> 10;                       // block-uniform (0:q 1:k 2:v)
    const float* bp = which == 0 ? bq : which == 1 ? bk : bv;
    const float scale = (which == 0) ? QSCALE : 1.0f;
    #pragma unroll
    for (int j = 0; j < 4; j++) {
      const int n = bn + wc * 64 + j * 16 + r0;
      const int dcol = n & 1023;
      const int h = dcol >> 6, hd = dcol & 63;
      const float bias = bp[dcol];
      // hd-dependent offsets, hoisted
      const int qk_d = ((hd >> 5) * 4 + ((hd >> 3) & 3)) * 128 + (hd & 7);
      const int v_d  = (hd >> 4) * 1024 + (hd & 15) * 8;
      #pragma unroll
      for (int i = 0; i < 4; i++)
        #pragma unroll
        for (int r = 0; r < 4; r++) {
          const int m = bm + wr * 64 + i * 16 + (lane >> 4) * 4 + r;
          const int b_ = m >> 11, s_ = m & 2047;
          const float v = (acc[i][j][r] + bias) * scale;
          if (which <= 1) {
            const size_t off = ((size_t)(b_ * NH + h) * (SEQ / 16) + (s_ >> 4)) * 1024
                             + qk_d + (s_ & 15) * 8;
            (which == 0 ? oq : ok)[off] = (bf16)v;
          } else {
            const size_t off = ((size_t)(b_ * NH + h) * (SEQ / 64) + (s_ >> 6)) * 4096
                             + v_d + ((s_ >> 5) & 1) * 512 + ((s_ >> 3) & 3) * 128 + (s_ & 7);
            ovt[off] = (bf16)v;
          }
        }
    }
  } else {
    #pragma unroll
    for (int j = 0; j < 4; j++) {
      const int n = bn + wc * 64 + j * 16 + r0;
      const float bias = bq[n];                        // o_b
      #pragma unroll
      for (int i = 0; i < 4; i++)
        #pragma unroll
        for (int r = 0; r < 4; r++) {
          const int m = bm + wr * 64 + i * 16 + (lane >> 4) * 4 + r;
          of[(size_t)m * DM + n] = acc[i][j][r] + bias;
        }
    }
  }
}

// ---------------- flash attention (swapped QK^T: lane-local softmax) ----------------
// grid (S/64, H, B), 256 threads = 4 waves, each wave owns 16 q-rows.
// sc = mfma(K_frag, Q_frag): lane holds S[k=16nf+4g+r][q=lane&15] -> row softmax is
// 15 in-lane fmax + 2 shfl_xor; m/l are per-lane scalars. P goes through a pad-72
// row-major LDS tile (b64 writes, b128 reads). PV = mfma(Vt_frag, P_frag) -> lane
// holds O[q=lane&15][d=df*16+g*4+r], written as 8B-vector stores.
__global__ __launch_bounds__(256) void attn_kernel(
    const bf16* __restrict__ Q, const bf16* __restrict__ Kf, const bf16* __restrict__ Vf,
    bf16* __restrict__ O) {
  const int tid = threadIdx.x;
  const int lane = tid & 63;
  const int wid = tid >> 6;
  const int g = lane >> 4;
  const int q = lane & 15;
  const int qt = blockIdx.x;
  const int h = blockIdx.y;
  const int b = blockIdx.z;

  const bf16* qp = Q  + ((size_t)(b * NH + h) * (SEQ / 16) + qt * 4) * 1024;
  const bf16* kp = Kf + (size_t)(b * NH + h) * (SEQ / 16) * 1024;
  const bf16* vp = Vf + (size_t)(b * NH + h) * (SEQ / 64) * 4096;

  __shared__ __align__(16) bf16 Ks[2][4096];
  __shared__ __align__(16) bf16 Vs[2][4096];     // fragment-ordered V tile
  __shared__ __align__(16) bf16 Pp[4][16 * 72];  // per-wave P[q][k], row stride 72 (pad)

  // stage Q (into Ks[1], read-once), K0, V0
  ASYNC16(&Ks[1][tid * 8], qp + tid * 8);
  ASYNC16(&Ks[1][2048 + tid * 8], qp + 2048 + tid * 8);
  ASYNC16(&Ks[0][tid * 8], kp + tid * 8);
  ASYNC16(&Ks[0][2048 + tid * 8], kp + 2048 + tid * 8);
  ASYNC16(&Vs[0][tid * 8], vp + tid * 8);
  ASYNC16(&Vs[0][2048 + tid * 8], vp + 2048 + tid * 8);
  __syncthreads();

  // Q fragments are loop-invariant: keep in registers (B-operand of swapped QK^T)
  const bf16x8 aq0 = *(const bf16x8*)&Ks[1][wid * 1024 + 0 * 512 + g * 128 + q * 8];
  const bf16x8 aq1 = *(const bf16x8*)&Ks[1][wid * 1024 + 1 * 512 + g * 128 + q * 8];
  __syncthreads();   // all waves done reading Q before Ks[1] is overwritten

  float m_run = -1e30f, l_run = 0.f;
  f32x4 oacc[4] = {};

  bf16* pw = &Pp[wid][q * 72 + g * 4];         // + nf*16 : write P[q][16nf+4g .. +3]
  const bf16* prd = &Pp[wid][q * 72 + g * 8];  // + c*32  : read  P[q][32c+8g .. +7]

  for (int kt = 0; kt < SEQ / 64; ++kt) {
    const int cur = kt & 1;
    if (kt + 1 < SEQ / 64) {
      const bf16* gk = kp + (size_t)(kt + 1) * 4096;
      ASYNC16(&Ks[cur ^ 1][tid * 8], gk + tid * 8);
      ASYNC16(&Ks[cur ^ 1][2048 + tid * 8], gk + 2048 + tid * 8);
      const bf16* gv = vp + (size_t)(kt + 1) * 4096;
      ASYNC16(&Vs[cur ^ 1][tid * 8], gv + tid * 8);
      ASYNC16(&Vs[cur ^ 1][2048 + tid * 8], gv + 2048 + tid * 8);
    }

    // ---- swapped QK^T: sc[nf][r] = S[k = nf*16 + g*4 + r][q] ----
    f32x4 sc[4] = {};
    __builtin_amdgcn_s_setprio(1);
    #pragma unroll
    for (int nf = 0; nf < 4; nf++) {
      const bf16x8 bk0 = *(const bf16x8*)&Ks[cur][nf * 1024 + 0 * 512 + g * 128 + q * 8];
      sc[nf] = __builtin_amdgcn_mfma_f32_16x16x32_bf16(bk0, aq0, sc[nf], 0, 0, 0);
      const bf16x8 bk1 = *(const bf16x8*)&Ks[cur][nf * 1024 + 1 * 512 + g * 128 + q * 8];
      sc[nf] = __builtin_amdgcn_mfma_f32_16x16x32_bf16(bk1, aq1, sc[nf], 0, 0, 0);
    }
    __builtin_amdgcn_s_setprio(0);

    // ---- online softmax: in-lane max over 16 + 2 shfl; defer-max (THR=8, log2) ----
    float pmax = fmaxf(fmaxf(sc[0][0], sc[0][1]), fmaxf(sc[0][2], sc[0][3]));
    #pragma unroll
    for (int nf = 1; nf < 4; nf++)
      pmax = fmaxf(pmax, fmaxf(fmaxf(sc[nf][0], sc[nf][1]), fmaxf(sc[nf][2], sc[nf][3])));
    pmax = fmaxf(pmax, __shfl_xor(pmax, 16));
    pmax = fmaxf(pmax, __shfl_xor(pmax, 32));

    if (__any(pmax > m_run + 8.f)) {
      const float mnew = fmaxf(m_run, pmax);
      const float fac = exp2f(m_run - mnew);
      l_run *= fac;
      #pragma unroll
      for (int df = 0; df < 4; df++)
        #pragma unroll
        for (int r = 0; r < 4; r++)
          oacc[df][r] *= fac;
      m_run = mnew;
    }

    float psum = 0.f;
    #pragma unroll
    for (int nf = 0; nf < 4; nf++) {
      bf16x4 pk;
      #pragma unroll
      for (int r = 0; r < 4; r++) {
        const float pv = exp2f(sc[nf][r] - m_run);
        psum += pv;
        pk[r] = (bf16)pv;
      }
      *(bf16x4*)(pw + nf * 16) = pk;   // ds_write_b64, P[q][16nf+4g..+3]
    }
    psum += __shfl_xor(psum, 16);
    psum += __shfl_xor(psum, 32);
    l_run += psum;

    // ---- swapped PV: oacc[df] += Vt_frag(df,c) x P_frag(c) ----
    __builtin_amdgcn_s_setprio(1);
    #pragma unroll
    for (int c = 0; c < 2; c++) {
      const bf16x8 pf = *(const bf16x8*)(prd + c * 32);
      #pragma unroll
      for (int df = 0; df < 4; df++) {
        const bf16x8 bv = *(const bf16x8*)&Vs[cur][df * 1024 + c * 512 + g * 128 + q * 8];
        oacc[df] = __builtin_amdgcn_mfma_f32_16x16x32_bf16(bv, pf, oacc[df], 0, 0, 0);
      }
    }
    __builtin_amdgcn_s_setprio(0);
    __syncthreads();   // K/V compute done + this iter's staging landed
  }

  // ---- epilogue: normalize, write attn output [B][S][D] (bf16, 8B vectors) ----
  const float inv = 1.0f / l_run;
  const int qrow = qt * 64 + wid * 16 + q;
  bf16* ob = (bf16*)&O[((size_t)b * SEQ + qrow) * DM + h * HDIM + g * 4];
  #pragma unroll
  for (int df = 0; df < 4; df++) {
    bf16x4 ov;
    #pragma unroll
    for (int r = 0; r < 4; r++) ov[r] = (bf16)(oacc[df][r] * inv);
    *(bf16x4*)(ob + df * 16) = ov;
  }
}

// ---------------- launcher ----------------
extern "C" void kernel_launch(void* const* d_in, const int* in_sizes, int n_in,
                              void* d_out, int out_size, void* d_ws, size_t ws_size,
                              hipStream_t stream) {
  (void)in_sizes; (void)n_in; (void)out_size; (void)ws_size;
  const float* x   = (const float*)d_in[0];
  const float* q_w = (const float*)d_in[1];
  const float* q_b = (const float*)d_in[2];
  const float* k_w = (const float*)d_in[3];
  const float* k_b = (const float*)d_in[4];
  const float* v_w = (const float*)d_in[5];
  const float* v_b = (const float*)d_in[6];
  const float* o_w = (const float*)d_in[7];
  const float* o_b = (const float*)d_in[8];
  float* out = (float*)d_out;

  char* p = (char*)d_ws;
  bf16* xb = (bf16*)p;  p += (size_t)MTOT * DM * 2;   // x bf16; reused later as attn output
  bf16* wt = (bf16*)p;  p += (size_t)4 * DM * DM * 2; // transposed bf16 weights [4][N][K]
  bf16* qq = (bf16*)p;  p += (size_t)MTOT * DM * 2;   // Q fragment-ordered (pre-scaled)
  bf16* kk = (bf16*)p;  p += (size_t)MTOT * DM * 2;   // K fragment-ordered
  bf16* vt = (bf16*)p;  p += (size_t)MTOT * DM * 2;   // V fragment-ordered

  cvt_x_kernel<<<1024, 256, 0, stream>>>(x, xb, MTOT * DM / 4);
  cvt_w_kernel<<<dim3(32, 32, 4), dim3(32, 8), 0, stream>>>(q_w, k_w, v_w, o_w, wt);

  // QKV projection: M=8192, N=3072 (q|k|v), K=1024
  gemm128<0><<<dim3(24, 64), 256, 0, stream>>>(xb, wt, q_b, k_b, v_b, qq, kk, vt, nullptr);

  // flash attention, writes [B][S][D] bf16 into xb (x no longer needed)
  attn_kernel<<<dim3(SEQ / 64, NH, NB), 256, 0, stream>>>(qq, kk, vt, xb);

  // output projection: M=8192, N=1024, K=1024, fp32 out + bias
  gemm128<1><<<dim3(8, 64), 256, 0, stream>>>(xb, wt + (size_t)3 * DM * DM, o_b, nullptr, nullptr,
                                              nullptr, nullptr, nullptr, out);
}